// Round 10
// baseline (1022.519 us; speedup 1.0000x reference)
//
#include <hip/hip_runtime.h>
#include <hip/hip_bf16.h>

// GATFusionBlockPosOnly: B=8, N=1024, D=256, 8 GAT heads, 4 CA heads.
// Round 10: GAT attention -> k_mattn3: NO LDS, NO barriers. V pre-transposed
// once in global (k_vtrans -> VtG[(h*8+b)][d][m], B-fragment layout), P built
// in A-layout registers, online row-sum, epilogue normalize. whcat region is
// reused for htcat after s1s2+vtrans consume it; VtG lives at 66-98MB.

#define BB 8
#define NN 1024
#define DD 256
#define HG 8
#define HC 4
#define BN (BB*NN)

typedef unsigned short u16;
typedef unsigned int u32;
typedef unsigned char u8;
typedef __attribute__((ext_vector_type(8))) short s8v;   // 8 bf16
typedef __attribute__((ext_vector_type(4))) float f4v;   // 4 fp32 acc
#define MFMA(a,b,c) __builtin_amdgcn_mfma_f32_16x16x32_bf16((a),(b),(c),0,0,0)

__device__ __forceinline__ u16 f2b(float x){
  union{ float f; unsigned u; } a; a.f = x;
  unsigned r = a.u + 0x7fff + ((a.u>>16)&1);
  return (u16)(r>>16);
}
__device__ __forceinline__ float b2f(u16 b){ return __uint_as_float(((unsigned)b)<<16); }
__device__ __forceinline__ float4 ld4bf(const u16* p){
  uint2 u = *(const uint2*)p;
  float4 r;
  r.x=__uint_as_float(u.x<<16); r.y=__uint_as_float(u.x&0xffff0000u);
  r.z=__uint_as_float(u.y<<16); r.w=__uint_as_float(u.y&0xffff0000u);
  return r;
}
__device__ __forceinline__ void load8(const float* p, float* v){
  float4 a=*(const float4*)p, b=*(const float4*)(p+4);
  v[0]=a.x;v[1]=a.y;v[2]=a.z;v[3]=a.w;v[4]=b.x;v[5]=b.y;v[6]=b.z;v[7]=b.w;
}
__device__ __forceinline__ float wredsum(float v){
  #pragma unroll
  for(int o=32;o>0;o>>=1) v += __shfl_xor(v,o);
  return v;
}
__device__ __forceinline__ float wredmax(float v){
  #pragma unroll
  for(int o=32;o>0;o>>=1) v = fmaxf(v,__shfl_xor(v,o));
  return v;
}
__device__ __forceinline__ float eluf(float x){ return x>0.f ? x : expm1f(x); }
__device__ __forceinline__ float leakyf(float z){ return z>=0.f ? z : 0.2f*z; }
__device__ __forceinline__ float exp0(float a){ return expf(fminf(a, 0.f)); }
__device__ __forceinline__ float flushf(float v){ return (fabsf(v) < 1.0e30f) ? v : 0.f; }

// ---------- fp32 -> (hi,lo) bf16 split ----------
__global__ __launch_bounds__(256) void k_split(const float* __restrict__ X, u16* __restrict__ H, u16* __restrict__ Lo){
  size_t i = ((size_t)blockIdx.x*256 + threadIdx.x)*8;
  float v[8]; load8(X+i, v);
  u16 hh[8], ll[8];
  #pragma unroll
  for (int j=0;j<8;j++){ hh[j]=f2b(v[j]); ll[j]=f2b(v[j]-b2f(hh[j])); }
  *(uint4*)(H+i)=*(uint4*)&hh[0];
  *(uint4*)(Lo+i)=*(uint4*)&ll[0];
}

// ---------- transpose fp32 [R][C] -> bf16 [C][R]; grid (C/64, R/64, slices) ----------
__global__ __launch_bounds__(256) void k_transpose(const float* __restrict__ S, u16* __restrict__ D,
                                                   int R, int sliceElems){
  __shared__ float tl[64][65];
  const float* src = S + (size_t)blockIdx.z*sliceElems;
  u16* dst = D + (size_t)blockIdx.z*sliceElems;
  int C = gridDim.x*64;
  int bx=blockIdx.x*64, by=blockIdx.y*64;
  int tid=threadIdx.x, r=tid>>2, c0=(tid&3)*16;
  #pragma unroll
  for (int i=0;i<16;i+=4){
    float4 v = *(const float4*)(src + (size_t)(by+r)*C + bx + c0 + i);
    tl[r][c0+i]=v.x; tl[r][c0+i+1]=v.y; tl[r][c0+i+2]=v.z; tl[r][c0+i+3]=v.w;
  }
  __syncthreads();
  u16 tmp[16];
  #pragma unroll
  for (int i=0;i<16;i++) tmp[i] = f2b(tl[c0+i][r]);
  *(uint4*)(dst + (size_t)(bx+r)*R + by + c0)     = *(uint4*)&tmp[0];
  *(uint4*)(dst + (size_t)(bx+r)*R + by + c0 + 8) = *(uint4*)&tmp[8];
}

// ---------- 4x 256x256 transposes in one launch (grid (4,4,4)) ----------
__global__ __launch_bounds__(256) void k_transpose4(const float* __restrict__ Sa, const float* __restrict__ Sb,
    const float* __restrict__ Sc, const float* __restrict__ Sd, u16* __restrict__ D){
  __shared__ float tl[64][65];
  const float* src = blockIdx.z==0 ? Sa : blockIdx.z==1 ? Sb : blockIdx.z==2 ? Sc : Sd;
  u16* dst = D + (size_t)blockIdx.z*65536;
  int bx=blockIdx.x*64, by=blockIdx.y*64;
  int tid=threadIdx.x, r=tid>>2, c0=(tid&3)*16;
  #pragma unroll
  for (int i=0;i<16;i+=4){
    float4 v = *(const float4*)(src + (size_t)(by+r)*256 + bx + c0 + i);
    tl[r][c0+i]=v.x; tl[r][c0+i+1]=v.y; tl[r][c0+i+2]=v.z; tl[r][c0+i+3]=v.w;
  }
  __syncthreads();
  u16 tmp[16];
  #pragma unroll
  for (int i=0;i<16;i++) tmp[i] = f2b(tl[c0+i][r]);
  *(uint4*)(dst + (size_t)(bx+r)*256 + by + c0)     = *(uint4*)&tmp[0];
  *(uint4*)(dst + (size_t)(bx+r)*256 + by + c0 + 8) = *(uint4*)&tmp[8];
}

// ---------- transpose + split: fp32 [256][256] -> hi/lo bf16 [256][256] ----------
__global__ __launch_bounds__(256) void k_transp_split(const float* __restrict__ S, u16* __restrict__ DH, u16* __restrict__ DL){
  __shared__ float tl[64][65];
  int bx=blockIdx.x*64, by=blockIdx.y*64;
  int tid=threadIdx.x, r=tid>>2, c0=(tid&3)*16;
  #pragma unroll
  for (int i=0;i<16;i+=4){
    float4 v = *(const float4*)(S + (size_t)(by+r)*256 + bx + c0 + i);
    tl[r][c0+i]=v.x; tl[r][c0+i+1]=v.y; tl[r][c0+i+2]=v.z; tl[r][c0+i+3]=v.w;
  }
  __syncthreads();
  u16 th[16], tll[16];
  #pragma unroll
  for (int i=0;i<16;i++){
    float v = tl[c0+i][r];
    th[i]=f2b(v); tll[i]=f2b(v - b2f(th[i]));
  }
  *(uint4*)(DH + (size_t)(bx+r)*256 + by + c0)     = *(uint4*)&th[0];
  *(uint4*)(DH + (size_t)(bx+r)*256 + by + c0 + 8) = *(uint4*)&th[8];
  *(uint4*)(DL + (size_t)(bx+r)*256 + by + c0)     = *(uint4*)&tll[0];
  *(uint4*)(DL + (size_t)(bx+r)*256 + by + c0 + 8) = *(uint4*)&tll[8];
}

// ---------- V transpose to B-frag layout: dst[(slice)][d][m] ----------
// WMODE: src = whcat [8192][2048], slice z=(h*8+b), cols h*256+...
// !WMODE: src [8192][ld=256], slice z=b.
template<typename ST, bool WMODE>
__global__ __launch_bounds__(256) void k_vtrans(const ST* __restrict__ src, u16* __restrict__ dst, int ldSrc){
  __shared__ u16 tl[64][72];
  int z = blockIdx.z;
  int b = WMODE ? (z&7) : z;
  int colOff = WMODE ? (z>>3)*256 : 0;
  int mBase = blockIdx.x*64, dBase = blockIdx.y*64;
  int tid=threadIdx.x, r=tid>>2, c0=(tid&3)*16;
  const ST* sp = src + ((size_t)b*1024 + mBase + r)*ldSrc + colOff + dBase + c0;
  if constexpr (sizeof(ST)==2){
    *(uint4*)&tl[r][c0]   = *(const uint4*)((const u16*)sp);
    *(uint4*)&tl[r][c0+8] = *(const uint4*)((const u16*)sp + 8);
  } else {
    float v[8]; u16 t8[8];
    load8((const float*)sp, v);
    #pragma unroll
    for (int i=0;i<8;i++) t8[i]=f2b(v[i]);
    *(uint4*)&tl[r][c0] = *(uint4*)&t8[0];
    load8((const float*)sp + 8, v);
    #pragma unroll
    for (int i=0;i<8;i++) t8[i]=f2b(v[i]);
    *(uint4*)&tl[r][c0+8] = *(uint4*)&t8[0];
  }
  __syncthreads();
  u16 tmp[16];
  #pragma unroll
  for (int i=0;i<16;i++) tmp[i] = tl[c0+i][r];
  u16* dp = dst + ((size_t)z*256 + dBase + r)*1024 + mBase + c0;
  *(uint4*)dp = *(uint4*)&tmp[0];
  *(uint4*)(dp+8) = *(uint4*)&tmp[8];
}

// ---------- pos_query ----------
__global__ __launch_bounds__(256) void k_posq(const float* __restrict__ x, const int* __restrict__ mask,
                                              float* __restrict__ pq, float* __restrict__ cnt){
  int b = blockIdx.x, chunk = blockIdx.y;
  int d = threadIdx.x;
  int n0 = chunk*64;
  float acc = 0.f; float c = 0.f;
  for (int i=0;i<64;i++){
    int n = n0+i;
    if (mask[b*NN+n]==1){ acc += x[((size_t)(b*NN+n))*DD + d]; c += 1.f; }
  }
  atomicAdd(&pq[b*DD+d], acc);
  if (d==0) atomicAdd(&cnt[b], c);
}

__global__ __launch_bounds__(256) void k_sq(const float* __restrict__ pq, const float* __restrict__ cnt,
                                            const float* __restrict__ Wq, float* __restrict__ sq){
  int b = blockIdx.x, e = threadIdx.x;
  float inv = 1.f / fmaxf(cnt[b], 1.f);
  float acc=0.f;
  for (int d0=0; d0<DD; d0++) acc += (pq[b*DD+d0]*inv) * Wq[d0*DD+e];
  sq[b*DD+e] = acc;
}

__global__ __launch_bounds__(256) void k_simsel(const float* __restrict__ y, const float* __restrict__ sq,
                                                float* __restrict__ simOut, u8* __restrict__ sel8){
  int r = blockIdx.x*4 + (threadIdx.x>>6);
  int lane = threadIdx.x & 63;
  int b = r>>10;
  float4 yv = *(const float4*)(y + (size_t)r*DD + lane*4);
  float4 qv = *(const float4*)(sq + b*DD + lane*4);
  float p = yv.x*qv.x + yv.y*qv.y + yv.z*qv.z + yv.w*qv.w;
  p = wredsum(p);
  if (lane==0){
    float s = p * 0.0625f;
    float sim = 1.f/(1.f+expf(-s));
    simOut[r] = sim;
    sel8[r] = (sim > 0.97f) ? 1 : 0;
  }
}

// ---------- no-LDS MFMA GEMM ----------
template<int EPI>
__global__ __launch_bounds__(256) void k_mgemm(const u16* __restrict__ A, const u16* __restrict__ BT,
    int KK, int ldB, float* __restrict__ C, const float* __restrict__ Xres,
    const float* __restrict__ gamma, u16* __restrict__ O){
  int tid=threadIdx.x, w=tid>>6, lane=tid&63, L=lane&15, q=lane>>4;
  int OC = gridDim.x<<6;
  int colBase=blockIdx.x<<6, rowBase=blockIdx.y<<6;
  const u16* ap = A + (size_t)(rowBase + w*16 + L)*KK + q*8;
  const u16* bp = BT + (size_t)(colBase + L)*ldB + q*8;
  size_t bs = (size_t)16*ldB;
  f4v z4={0.f,0.f,0.f,0.f};
  f4v acc[4]={z4,z4,z4,z4};
  s8v a0 = *(const s8v*)ap;
  s8v b0 = *(const s8v*)bp;
  s8v b1 = *(const s8v*)(bp + bs);
  s8v b2 = *(const s8v*)(bp + 2*bs);
  s8v b3 = *(const s8v*)(bp + 3*bs);
  for (int k0=32;k0<KK;k0+=32){
    s8v an  = *(const s8v*)(ap + k0);
    s8v bn0 = *(const s8v*)(bp + k0);
    s8v bn1 = *(const s8v*)(bp + bs + k0);
    s8v bn2 = *(const s8v*)(bp + 2*bs + k0);
    s8v bn3 = *(const s8v*)(bp + 3*bs + k0);
    acc[0]=MFMA(a0,b0,acc[0]); acc[1]=MFMA(a0,b1,acc[1]);
    acc[2]=MFMA(a0,b2,acc[2]); acc[3]=MFMA(a0,b3,acc[3]);
    a0=an; b0=bn0; b1=bn1; b2=bn2; b3=bn3;
  }
  acc[0]=MFMA(a0,b0,acc[0]); acc[1]=MFMA(a0,b1,acc[1]);
  acc[2]=MFMA(a0,b2,acc[2]); acc[3]=MFMA(a0,b3,acc[3]);
  #pragma unroll
  for (int t=0;t<4;t++){
    int col = colBase + t*16 + L;
    #pragma unroll
    for (int reg=0;reg<4;reg++){
      int row = rowBase + w*16 + q*4 + reg;
      size_t off = (size_t)row*OC + col;
      float v = acc[t][reg];
      if constexpr (EPI==0){ C[off] = v; }
      else if constexpr (EPI==1){ C[off] += v; }
      else if constexpr (EPI==2){ C[off] = flushf(Xres[off] + gamma[col]*v); }
      else { O[off] = f2b(v); }
    }
  }
}

// ---------- fused q/k/v projections ----------
__global__ __launch_bounds__(256) void k_mgemm3(const u16* __restrict__ Aq, const u16* __restrict__ Akv,
    const u16* __restrict__ BT0, u16* __restrict__ O0){
  int tid=threadIdx.x, w=tid>>6, lane=tid&63, L=lane&15, q=lane>>4;
  const u16* A = blockIdx.z==0 ? Aq : Akv;
  const u16* BT = BT0 + (size_t)blockIdx.z*65536;
  u16* O = O0 + (size_t)blockIdx.z*2097152;
  int colBase=blockIdx.x<<6, rowBase=blockIdx.y<<6;
  const u16* ap = A + (size_t)(rowBase + w*16 + L)*256 + q*8;
  const u16* bp = BT + (size_t)(colBase + L)*256 + q*8;
  size_t bs = (size_t)16*256;
  f4v z4={0.f,0.f,0.f,0.f};
  f4v acc[4]={z4,z4,z4,z4};
  #pragma unroll
  for (int k0=0;k0<256;k0+=32){
    s8v a0 = *(const s8v*)(ap + k0);
    #pragma unroll
    for (int t=0;t<4;t++){
      s8v bt = *(const s8v*)(bp + (size_t)t*bs + k0);
      acc[t]=MFMA(a0,bt,acc[t]);
    }
  }
  #pragma unroll
  for (int t=0;t<4;t++){
    int col = colBase + t*16 + L;
    #pragma unroll
    for (int reg=0;reg<4;reg++){
      int row = rowBase + w*16 + q*4 + reg;
      O[(size_t)row*256 + col] = f2b(acc[t][reg]);
    }
  }
}

// ---------- split (3-term) MFMA GEMM ----------
template<int EPI>
__global__ __launch_bounds__(256) void k_msgemm(const u16* __restrict__ Ah, const u16* __restrict__ Al,
    const u16* __restrict__ Bh, const u16* __restrict__ Bl,
    float* __restrict__ C, u16* __restrict__ Oh, u16* __restrict__ Ol){
  int tid=threadIdx.x, w=tid>>6, lane=tid&63, L=lane&15, q=lane>>4;
  int colBase=blockIdx.x<<6, rowBase=blockIdx.y<<6;
  const u16* ahp = Ah + (size_t)(rowBase + w*16 + L)*256 + q*8;
  const u16* alp = Al + (size_t)(rowBase + w*16 + L)*256 + q*8;
  const u16* bhp = Bh + (size_t)(colBase + L)*256 + q*8;
  const u16* blp = Bl + (size_t)(colBase + L)*256 + q*8;
  f4v z4={0.f,0.f,0.f,0.f};
  f4v acc[4]={z4,z4,z4,z4};
  for (int k0=0;k0<256;k0+=32){
    s8v ah=*(const s8v*)(ahp+k0), al=*(const s8v*)(alp+k0);
    #pragma unroll
    for (int t=0;t<4;t++){
      s8v bh=*(const s8v*)(bhp + (size_t)t*16*256 + k0);
      s8v bl=*(const s8v*)(blp + (size_t)t*16*256 + k0);
      acc[t]=MFMA(ah,bh,acc[t]);
      acc[t]=MFMA(ah,bl,acc[t]);
      acc[t]=MFMA(al,bh,acc[t]);
    }
  }
  #pragma unroll
  for (int t=0;t<4;t++){
    int col = colBase + t*16 + L;
    #pragma unroll
    for (int reg=0;reg<4;reg++){
      int row = rowBase + w*16 + q*4 + reg;
      size_t off = (size_t)row*256 + col;
      float v = acc[t][reg];
      if constexpr (EPI==0){ C[off] = v; }
      else { u16 h = f2b(v); Oh[off]=h; Ol[off]=f2b(v - b2f(h)); }
    }
  }
}

// ---------- split MFMA gram + bitpack ----------
__global__ __launch_bounds__(256) void k_mconnect(const u16* __restrict__ fah, const u16* __restrict__ fal,
    const u8* __restrict__ sel8, u32* __restrict__ conn){
  __shared__ u8 sg[64][64];
  int tid=threadIdx.x, w=tid>>6, lane=tid&63, L=lane&15, q=lane>>4;
  int b=blockIdx.z;
  int mBase=blockIdx.x*64, nBase=blockIdx.y*64;
  size_t bOff=(size_t)b*NN;
  const u16* ahp = fah + (bOff + nBase + w*16 + L)*256 + q*8;
  const u16* alp = fal + (bOff + nBase + w*16 + L)*256 + q*8;
  const u16* bhp = fah + (bOff + mBase + L)*256 + q*8;
  const u16* blp = fal + (bOff + mBase + L)*256 + q*8;
  f4v z4={0.f,0.f,0.f,0.f};
  f4v acc[4]={z4,z4,z4,z4};
  for (int k0=0;k0<256;k0+=32){
    s8v ah=*(const s8v*)(ahp+k0), al=*(const s8v*)(alp+k0);
    #pragma unroll
    for (int t=0;t<4;t++){
      s8v bh=*(const s8v*)(bhp + (size_t)t*16*256 + k0);
      s8v bl=*(const s8v*)(blp + (size_t)t*16*256 + k0);
      acc[t]=MFMA(ah,bh,acc[t]);
      acc[t]=MFMA(ah,bl,acc[t]);
      acc[t]=MFMA(al,bh,acc[t]);
    }
  }
  #pragma unroll
  for (int t=0;t<4;t++)
    #pragma unroll
    for (int reg=0;reg<4;reg++)
      sg[w*16 + q*4 + reg][t*16 + L] = acc[t][reg] > 0.f;
  __syncthreads();
  if (tid<128){
    int row=tid>>1, ww=tid&1;
    int nG = nBase+row;
    u32 word=0;
    if (sel8[b*NN + nG]){
      for (int j=0;j<32;j++){
        int m = mBase + ww*32 + j;
        if (sg[row][ww*32+j] && sel8[b*NN+m]) word |= (1u<<j);
      }
    }
    conn[((size_t)b*NN + nG)*32 + (mBase>>5) + ww] = word;
  }
}

// ---------- s1/s2 ----------
template<typename VT>
__global__ __launch_bounds__(256) void k_s1s2(const VT* __restrict__ V, int ldV, int colStep,
    const float* __restrict__ a1, const float* __restrict__ a2, int aStep,
    float* __restrict__ s1a, float* __restrict__ s2a){
  int h = blockIdx.y;
  int r = blockIdx.x*4 + (threadIdx.x>>6);
  int lane = threadIdx.x&63;
  float4 v;
  if constexpr (sizeof(VT)==2) v = ld4bf((const u16*)V + (size_t)r*ldV + h*colStep + lane*4);
  else                         v = *(const float4*)((const float*)V + (size_t)r*ldV + h*colStep + lane*4);
  const float* a1p = a1 + h*aStep; const float* a2p = a2 + h*aStep;
  float4 w1 = *(const float4*)(a1p+lane*4), w2 = *(const float4*)(a2p+lane*4);
  float d1 = v.x*w1.x+v.y*w1.y+v.z*w1.z+v.w*w1.w;
  float d2 = v.x*w2.x+v.y*w2.y+v.z*w2.z+v.w*w2.w;
  d1=wredsum(d1); d2=wredsum(d2);
  if (lane==0){ s1a[h*BN+r]=d1; s2a[h*BN+r]=d2; }
}

// ---------- row max of s2 over connected m ----------
__global__ __launch_bounds__(256) void k_rowmax(const float* __restrict__ s2a,
    const u32* __restrict__ conn, float* __restrict__ M2a){
  int h = blockIdx.y;
  int r = blockIdx.x*4 + (threadIdx.x>>6);
  int lane = threadIdx.x&63;
  int b = r>>10;
  const float* s2p = s2a + h*BN + b*NN;
  float mx = -3.0e38f;
  #pragma unroll
  for (int t=0;t<16;t++){
    int m = lane + t*64;
    u32 wd = conn[(size_t)r*32 + (m>>5)];
    if ((wd>>(m&31))&1u) mx = fmaxf(mx, s2p[m]);
  }
  mx = wredmax(mx);
  if (lane==0) M2a[h*BN+r] = mx;
}

// ---------- MFMA GAT attention v4: no LDS, no barriers ----------
// grid (256/(NT*16), 128, Z). V = VtG[(z*8+b)][d][m] (B-frag layout).
// Out col = z*256 + colBase + t*16 + L; row sums online; normalize in epilogue.
template<int NT>
__global__ __launch_bounds__(256) void k_mattn3(const float* __restrict__ s1a, const float* __restrict__ s2a,
    const float* __restrict__ M2a, const u32* __restrict__ conn,
    const u16* __restrict__ VtG, u16* __restrict__ Out, int oStride){
  int tid=threadIdx.x, w=tid>>6, lane=tid&63, L=lane&15, q=lane>>4;
  int colBase = blockIdx.x*(NT*16);
  int rowBase = blockIdx.y*64;
  int z = blockIdx.z;
  int sOff = z*BN;
  int b = rowBase>>10;
  size_t bOff = (size_t)b*NN;
  int r = rowBase + w*16 + L;
  float s1v = s1a[sOff+r];
  float rmv = leakyf(s1v + M2a[sOff+r]);
  const float* s2p = s2a + sOff + bOff;
  const u16* vb0 = VtG + ((size_t)(z*8 + b))*262144 + (size_t)(colBase + L)*1024 + q*8;
  f4v z4={0.f,0.f,0.f,0.f};
  f4v acc[NT];
  #pragma unroll
  for (int t=0;t<NT;t++) acc[t]=z4;
  float sumP = 0.f;
  for (int k0=0;k0<NN;k0+=32){
    u32 cw = conn[(size_t)r*32 + (k0>>5)];
    float4 sA = *(const float4*)(s2p + k0 + q*8);
    float4 sB = *(const float4*)(s2p + k0 + q*8 + 4);
    float sv[8] = {sA.x,sA.y,sA.z,sA.w,sB.x,sB.y,sB.z,sB.w};
    s8v pf;
    #pragma unroll
    for (int j=0;j<8;j++){
      float ev = ((cw>>(q*8+j))&1u) ? leakyf(s1v + sv[j]) : -9.0e15f;
      float p = exp0(ev - rmv);
      sumP += p;
      pf[j] = (short)f2b(p);
    }
    #pragma unroll
    for (int t=0;t<NT;t++){
      s8v vf = *(const s8v*)(vb0 + (size_t)t*16384 + k0);
      acc[t] = MFMA(pf, vf, acc[t]);
    }
  }
  sumP += __shfl_xor(sumP,16);
  sumP += __shfl_xor(sumP,32);
  float rsi[4];
  #pragma unroll
  for (int reg=0;reg<4;reg++) rsi[reg] = 1.f / __shfl(sumP, q*4+reg);
  #pragma unroll
  for (int t=0;t<NT;t++){
    int col = z*256 + colBase + t*16 + L;
    #pragma unroll
    for (int reg=0;reg<4;reg++){
      int row = rowBase + w*16 + q*4 + reg;
      Out[(size_t)row*oStride + col] = f2b(eluf(acc[t][reg]*rsi[reg]));
    }
  }
}

// ---------- LayerNorms ----------
__global__ __launch_bounds__(256) void k_ln_x(const float* __restrict__ x, const float* __restrict__ g,
                                              const float* __restrict__ bb, u16* __restrict__ out){
  int r = blockIdx.x*4 + (threadIdx.x>>6);
  int lane=threadIdx.x&63;
  float4 v = *(const float4*)(x + (size_t)r*DD + lane*4);
  float s = v.x+v.y+v.z+v.w;
  float s2 = v.x*v.x+v.y*v.y+v.z*v.z+v.w*v.w;
  s = wredsum(s); s2 = wredsum(s2);
  float mean = s*(1.f/256.f);
  float var = s2*(1.f/256.f) - mean*mean;
  float rstd = rsqrtf(var + 1e-5f);
  float4 gv = *(const float4*)(g+lane*4), bv = *(const float4*)(bb+lane*4);
  u16 t[4];
  t[0]=f2b((v.x-mean)*rstd*gv.x+bv.x); t[1]=f2b((v.y-mean)*rstd*gv.y+bv.y);
  t[2]=f2b((v.z-mean)*rstd*gv.z+bv.z); t[3]=f2b((v.w-mean)*rstd*gv.w+bv.w);
  *(uint2*)(out + (size_t)r*DD + lane*4) = *(uint2*)&t[0];
}

__global__ __launch_bounds__(256) void k_ln_kv(const u16* __restrict__ gout, const float* __restrict__ pe,
    const u8* __restrict__ sel8, const float* __restrict__ g, const float* __restrict__ bb,
    u16* __restrict__ out){
  int r = blockIdx.x*4 + (threadIdx.x>>6);
  int lane=threadIdx.x&63;
  int n = r & 1023;
  float4 v = make_float4(0.f,0.f,0.f,0.f);
  if (sel8[r]){
    float4 gv = ld4bf(gout + (size_t)r*DD + lane*4);
    float4 pv = *(const float4*)(pe + (size_t)n*DD + lane*4);
    v = make_float4(gv.x+pv.x, gv.y+pv.y, gv.z+pv.z, gv.w+pv.w);
  }
  float s = v.x+v.y+v.z+v.w;
  float s2 = v.x*v.x+v.y*v.y+v.z*v.z+v.w*v.w;
  s = wredsum(s); s2 = wredsum(s2);
  float mean = s*(1.f/256.f);
  float var = s2*(1.f/256.f) - mean*mean;
  float rstd = rsqrtf(var + 1e-5f);
  float4 gv = *(const float4*)(g+lane*4), bv = *(const float4*)(bb+lane*4);
  u16 t[4];
  t[0]=f2b((v.x-mean)*rstd*gv.x+bv.x); t[1]=f2b((v.y-mean)*rstd*gv.y+bv.y);
  t[2]=f2b((v.z-mean)*rstd*gv.z+bv.z); t[3]=f2b((v.w-mean)*rstd*gv.w+bv.w);
  *(uint2*)(out + (size_t)r*DD + lane*4) = *(uint2*)&t[0];
}

// ---------- CA max pass (exp-free) ----------
__global__ __launch_bounds__(256) void k_mca_max(const u16* __restrict__ q, const u16* __restrict__ k,
    const u8* __restrict__ sel8, float* __restrict__ cmax){
  __shared__ __align__(16) u16 Qls[64][72];
  __shared__ __align__(16) u16 Kls[64][72];
  __shared__ float cw4[4];
  int tid=threadIdx.x;
  int w = tid>>6, lane = tid&63, L = lane&15, qd = lane>>4;
  int b=blockIdx.z, h=blockIdx.y, rowBase=blockIdx.x*64;
  size_t bOff = (size_t)b*NN;
  {
    float c = 0.f;
    #pragma unroll
    for (int i=0;i<4;i++) c += sel8[b*NN + tid*4 + i] ? 0.f : 1.f;
    c = wredsum(c);
    if (lane==0) cw4[w]=c;
  }
  {
    int r=tid>>2, c0=(tid&3)*16;
    size_t base = (bOff + rowBase + r)*(size_t)DD + h*64 + c0;
    *(uint4*)&Qls[r][c0]   = *(const uint4*)(q + base);
    *(uint4*)&Qls[r][c0+8] = *(const uint4*)(q + base + 8);
  }
  float um[4];
  #pragma unroll
  for (int i=0;i<4;i++) um[i]=-3.0e38f;
  for (int m0=0;m0<NN;m0+=64){
    __syncthreads();
    {
      int r=tid>>2, c0=(tid&3)*16;
      size_t base = (bOff + m0 + r)*(size_t)DD + h*64 + c0;
      *(uint4*)&Kls[r][c0]   = *(const uint4*)(k + base);
      *(uint4*)&Kls[r][c0+8] = *(const uint4*)(k + base + 8);
    }
    __syncthreads();
    f4v zero = {0.f,0.f,0.f,0.f};
    f4v sa[4] = {zero,zero,zero,zero};
    #pragma unroll
    for (int kc=0;kc<64;kc+=32){
      s8v af = *(const s8v*)&Qls[w*16 + L][kc + qd*8];
      #pragma unroll
      for (int t=0;t<4;t++){
        s8v bfr = *(const s8v*)&Kls[t*16 + L][kc + qd*8];
        sa[t] = MFMA(af, bfr, sa[t]);
      }
    }
    #pragma unroll
    for (int t=0;t<4;t++){
      int m = m0 + t*16 + L;
      if (sel8[b*NN+m]){
        #pragma unroll
        for (int reg=0;reg<4;reg++) um[reg] = fmaxf(um[reg], sa[t][reg]*0.125f);
      }
    }
  }
  #pragma unroll
  for (int off=1;off<16;off<<=1)
    #pragma unroll
    for (int reg=0;reg<4;reg++) um[reg] = fmaxf(um[reg], __shfl_xor(um[reg],off));
  __syncthreads();
  float cn = cw4[0]+cw4[1]+cw4[2]+cw4[3];
  if (L==0){
    #pragma unroll
    for (int reg=0;reg<4;reg++){
      int row = rowBase + w*16 + qd*4 + reg;
      float M = um[reg];
      if (cn>0.f) M = fmaxf(M, -1.0e9f);
      cmax[((size_t)b*HC+h)*NN + row] = M;
    }
  }
}

// ---------- CA attention (epilogue-normalized) ----------
__global__ __launch_bounds__(256) void k_mca_av(const u16* __restrict__ q, const u16* __restrict__ k,
    const u16* __restrict__ v, const u8* __restrict__ sel8,
    const float* __restrict__ cmax, u16* __restrict__ O){
  __shared__ __align__(16) u16 Qls[64][72];
  __shared__ __align__(16) u16 KP[64][72];
  __shared__ __align__(16) u16 Vt[64][72];
  int tid=threadIdx.x;
  int w = tid>>6, lane = tid&63, L = lane&15, qd = lane>>4;
  int b=blockIdx.z, h=blockIdx.y, rowBase=blockIdx.x*64;
  size_t bOff = (size_t)b*NN;
  {
    int r=tid>>2, c0=(tid&3)*16;
    size_t base = (bOff + rowBase + r)*(size_t)DD + h*64 + c0;
    *(uint4*)&Qls[r][c0]   = *(const uint4*)(q + base);
    *(uint4*)&Qls[r][c0+8] = *(const uint4*)(q + base + 8);
  }
  float rm[4], sp[4];
  #pragma unroll
  for (int reg=0;reg<4;reg++){
    rm[reg]=cmax[((size_t)b*HC+h)*NN + rowBase + w*16 + qd*4 + reg];
    sp[reg]=0.f;
  }
  f4v zero = {0.f,0.f,0.f,0.f};
  f4v acc[4] = {zero,zero,zero,zero};
  int svm = tid&63, svd0 = (tid>>6)*16;
  for (int m0=0;m0<NN;m0+=64){
    __syncthreads();
    {
      int r=tid>>2, c0=(tid&3)*16;
      size_t base = (bOff + m0 + r)*(size_t)DD + h*64 + c0;
      *(uint4*)&KP[r][c0]   = *(const uint4*)(k + base);
      *(uint4*)&KP[r][c0+8] = *(const uint4*)(k + base + 8);
      size_t vb_ = (bOff + m0 + svm)*(size_t)DD + h*64 + svd0;
      uint4 u0 = *(const uint4*)(v + vb_);
      uint4 u1 = *(const uint4*)(v + vb_ + 8);
      u16 tmp[16];
      *(uint4*)&tmp[0]=u0; *(uint4*)&tmp[8]=u1;
      #pragma unroll
      for (int i=0;i<16;i++) Vt[svd0+i][svm] = tmp[i];
    }
    __syncthreads();
    f4v sa[4] = {zero,zero,zero,zero};
    #pragma unroll
    for (int kc=0;kc<64;kc+=32){
      s8v af = *(const s8v*)&Qls[w*16 + L][kc + qd*8];
      #pragma unroll
      for (int t=0;t<4;t++){
        s8v bfr = *(const s8v*)&KP[t*16 + L][kc + qd*8];
        sa[t] = MFMA(af, bfr, sa[t]);
      }
    }
    __syncthreads();
    #pragma unroll
    for (int t=0;t<4;t++){
      int m = m0 + t*16 + L;
      bool sl = sel8[b*NN+m];
      #pragma unroll
      for (int reg=0;reg<4;reg++){
        float val = sl ? sa[t][reg]*0.125f : -1.0e9f;
        float pv = exp0(val - rm[reg]);
        sp[reg] += pv;
        KP[w*16 + qd*4 + reg][t*16 + L] = f2b(pv);
      }
    }
    __syncthreads();
    #pragma unroll
    for (int mc=0;mc<64;mc+=32){
      s8v pf = *(const s8v*)&KP[w*16 + L][mc + qd*8];
      #pragma unroll
      for (int t=0;t<4;t++){
        s8v vf = *(const s8v*)&Vt[t*16 + L][mc + qd*8];
        acc[t] = MFMA(pf, vf, acc[t]);
      }
    }
  }
  #pragma unroll
  for (int off=1;off<16;off<<=1)
    #pragma unroll
    for (int reg=0;reg<4;reg++) sp[reg] += __shfl_xor(sp[reg],off);
  float ri[4];
  #pragma unroll
  for (int reg=0;reg<4;reg++) ri[reg] = 1.f/sp[reg];
  #pragma unroll
  for (int t=0;t<4;t++){
    int col = h*64 + t*16 + L;
    #pragma unroll
    for (int reg=0;reg<4;reg++){
      int row = rowBase + w*16 + qd*4 + reg;
      O[(bOff + row)*(size_t)DD + col] = f2b(acc[t][reg]*ri[reg]);
    }
  }
}

extern "C" void kernel_launch(void* const* d_in, const int* in_sizes, int n_in,
                              void* d_out, int out_size, void* d_ws, size_t ws_size,
                              hipStream_t stream) {
  (void)in_sizes; (void)n_in; (void)out_size;
  const float* x      = (const float*)d_in[0];
  const int*   mask   = (const int*  )d_in[1];
  const float* pe     = (const float*)d_in[2];
  const float* sim_Wx = (const float*)d_in[3];
  const float* sim_Wq = (const float*)d_in[4];
  const float* adj_W  = (const float*)d_in[5];
  const float* gat_W  = (const float*)d_in[6];
  const float* gat_a1 = (const float*)d_in[7];
  const float* gat_a2 = (const float*)d_in[8];
  const float* gat_Wo = (const float*)d_in[9];
  const float* gat_ao1= (const float*)d_in[10];
  const float* gat_ao2= (const float*)d_in[11];
  const float* ln3_g  = (const float*)d_in[12];
  const float* ln3_b  = (const float*)d_in[13];
  const float* ln4_g  = (const float*)d_in[14];
  const float* ln4_b  = (const float*)d_in[15];
  const float* ca_Wq  = (const float*)d_in[16];
  const float* ca_Wk  = (const float*)d_in[17];
  const float* ca_Wv  = (const float*)d_in[18];
  const float* ca_Wp  = (const float*)d_in[19];
  const float* gamma  = (const float*)d_in[20];
  float* out    = (float*)d_out;
  float* simOut = out + (size_t)BN*DD;

  const size_t MB = 1024*1024;
  bool big = ws_size >= 98*MB;
  char* W = (char*)d_ws;
  float* pq   = (float*)W;
  float* cnt  = pq + 2048;
  float* sq   = cnt + 16;
  float* s1a  = (float*)(W + 64*1024);
  float* s2a  = (float*)(W + 320*1024);
  float* M2a  = (float*)(W + 576*1024);
  float* cam  = (float*)(W + 1088*1024);
  u8*    sel8 = (u8*)(W + 1400*1024);
  u32*   conn = (u32*)(W + 2*MB);
  u16*   WT0  = (u16*)(W + 3*MB);
  u16*   WoT  = (u16*)(W + 4*MB);
  u16*   WQT  = (u16*)(W + 5*MB);
  u16*   WKT  = WQT + 65536;
  u16*   WVT  = WKT + 65536;
  u16*   WPT  = WVT + 65536;
  u16*   sWxh = (u16*)(W + 5*MB + 512*1024);
  u16*   sWxl = sWxh + 65536;
  u16*   aWh  = sWxl + 65536;
  u16*   aWl  = aWh + 65536;
  u16*   xh   = (u16*)(W + 6*MB);
  u16*   xl   = (u16*)(W + 10*MB);     // dead after msgemm phase -> Vt scratch (fallback)
  float* S0   = (float*)(W + 14*MB);
  u16*   fah  = (u16*)(W + 22*MB);
  u16*   fal  = (u16*)(W + 26*MB);
  u16*   T2   = (u16*)(W + 30*MB);

  // prep
  k_split<<<BN*DD/2048,256,0,stream>>>(x, xh, xl);
  k_transpose<<<dim3(4,4,HG),256,0,stream>>>(gat_W, WT0, 256, 65536);
  k_transpose<<<dim3(4,32,1),256,0,stream>>>(gat_Wo, WoT, 2048, 0);
  k_transpose4<<<dim3(4,4,4),256,0,stream>>>(ca_Wq, ca_Wk, ca_Wv, ca_Wp, WQT);
  k_transp_split<<<dim3(4,4,1),256,0,stream>>>(sim_Wx, sWxh, sWxl);
  k_transp_split<<<dim3(4,4,1),256,0,stream>>>(adj_W, aWh, aWl);

  hipMemsetAsync(pq, 0, (2048+16)*sizeof(float), stream);
  k_posq<<<dim3(BB,16),256,0,stream>>>(x, mask, pq, cnt);
  k_sq<<<BB,256,0,stream>>>(pq, cnt, sim_Wq, sq);
  k_msgemm<0><<<dim3(4,128),256,0,stream>>>(xh, xl, sWxh, sWxl, S0, nullptr, nullptr);  // y
  k_simsel<<<BN/4,256,0,stream>>>(S0, sq, simOut, sel8);
  k_msgemm<4><<<dim3(4,128),256,0,stream>>>(xh, xl, aWh, aWl, nullptr, fah, fal);       // fa split
  k_mconnect<<<dim3(16,16,BB),256,0,stream>>>(fah, fal, sel8, conn);

  if (big){
    u16* whcat = (u16*)(W + 34*MB);    // [8192][2048]; dead after s1s2+vtrans
    u16* htcat = (u16*)(W + 34*MB);    // overwrites whcat
    u16* VtG   = (u16*)(W + 66*MB);    // 32MB: V in B-frag layout [(h*8+b)][d][m]
    u16* qx = (u16*)(W + 34*MB);       // CA bufs (htcat dead after Who GEMM)
    u16* kv = (u16*)(W + 38*MB);
    u16* qb = (u16*)(W + 42*MB);
    u16* vb = (u16*)(W + 50*MB);
    u16* Ob = (u16*)(W + 54*MB);

    k_mgemm<3><<<dim3(32,128),256,0,stream>>>(xh, WT0, 256, 256, nullptr, nullptr, nullptr, whcat); // Wh_cat
    k_s1s2<u16><<<dim3(BN/4,HG),256,0,stream>>>(whcat, 2048, 256, gat_a1, gat_a2, 256, s1a, s2a);
    k_rowmax<<<dim3(BN/4,HG),256,0,stream>>>(s2a, conn, M2a);
    k_vtrans<u16,true><<<dim3(16,4,64),256,0,stream>>>(whcat, VtG, 2048);
    k_mattn3<16><<<dim3(1,128,HG),256,0,stream>>>(s1a, s2a, M2a, conn, VtG, htcat, 2048);
    k_mgemm<0><<<dim3(4,128),256,0,stream>>>(htcat, WoT, 2048, 2048, S0, nullptr, nullptr, nullptr); // Who fp32
    k_s1s2<float><<<dim3(BN/4,1),256,0,stream>>>(S0, 256, 0, gat_ao1, gat_ao2, 0, s1a, s2a);
    k_rowmax<<<dim3(BN/4,1),256,0,stream>>>(s2a, conn, M2a);
    k_vtrans<float,false><<<dim3(16,4,8),256,0,stream>>>(S0, VtG, 256);
    k_mattn3<8><<<dim3(2,128,1),256,0,stream>>>(s1a, s2a, M2a, conn, VtG, T2, 256);   // gout

    k_ln_x<<<BN/4,256,0,stream>>>(x, ln3_g, ln3_b, qx);
    k_ln_kv<<<BN/4,256,0,stream>>>(T2, pe, sel8, ln4_g, ln4_b, kv);
    k_mgemm3<<<dim3(4,128,3),256,0,stream>>>(qx, kv, WQT, qb);     // qb,kb,vb (stride 4MB)
    k_mca_max<<<dim3(16,HC,BB),256,0,stream>>>(qb, qb + 2097152, sel8, cam);
    k_mca_av<<<dim3(16,HC,BB),256,0,stream>>>(qb, qb + 2097152, vb, sel8, cam, Ob);
    k_mgemm<2><<<dim3(4,128),256,0,stream>>>(Ob, WPT, 256, 256, out, x, gamma, nullptr);
  } else {
    u16* T0 = fah;
    u16* T1 = fal;
    u16* VtF = xl;                     // 4MB Vt scratch (xl dead)
    u16* S0b = (u16*)S0;
    hipMemsetAsync(S0, 0, 8*MB, stream);
    for (int h=0;h<HG;h++){
      k_mgemm<3><<<dim3(4,128),256,0,stream>>>(xh, WT0 + (size_t)h*65536, 256, 256, nullptr, nullptr, nullptr, T0);
      k_s1s2<u16><<<dim3(BN/4,1),256,0,stream>>>(T0, 256, 0, gat_a1 + h*DD, gat_a2 + h*DD, 0, s1a, s2a);
      k_rowmax<<<dim3(BN/4,1),256,0,stream>>>(s2a, conn, M2a);
      k_vtrans<u16,false><<<dim3(16,4,8),256,0,stream>>>(T0, VtF, 256);
      k_mattn3<8><<<dim3(2,128,1),256,0,stream>>>(s1a, s2a, M2a, conn, VtF, T1, 256);
      k_mgemm<1><<<dim3(4,128),256,0,stream>>>(T1, WoT + (size_t)h*256, 256, 2048, S0, nullptr, nullptr, nullptr);
    }
    k_s1s2<float><<<dim3(BN/4,1),256,0,stream>>>(S0, 256, 0, gat_ao1, gat_ao2, 0, s1a, s2a);
    k_rowmax<<<dim3(BN/4,1),256,0,stream>>>(s2a, conn, M2a);
    k_vtrans<float,false><<<dim3(16,4,8),256,0,stream>>>(S0, VtF, 256);
    k_mattn3<8><<<dim3(2,128,1),256,0,stream>>>(s1a, s2a, M2a, conn, VtF, T2, 256);  // gout

    k_ln_x<<<BN/4,256,0,stream>>>(x, ln3_g, ln3_b, T1);
    k_ln_kv<<<BN/4,256,0,stream>>>(T2, pe, sel8, ln4_g, ln4_b, T0);
    k_mgemm<3><<<dim3(4,128),256,0,stream>>>(T1, WQT, 256, 256, nullptr, nullptr, nullptr, T2);
    k_mgemm<3><<<dim3(4,128),256,0,stream>>>(T0, WKT, 256, 256, nullptr, nullptr, nullptr, T1);
    k_mgemm<3><<<dim3(4,128),256,0,stream>>>(T0, WVT, 256, 256, nullptr, nullptr, nullptr, S0b);
    k_mca_max<<<dim3(16,HC,BB),256,0,stream>>>(T2, T1, sel8, cam);
    k_mca_av<<<dim3(16,HC,BB),256,0,stream>>>(T2, T1, S0b, sel8, cam, T0);
    k_mgemm<2><<<dim3(4,128),256,0,stream>>>(T0, WPT, 256, 256, out, x, gamma, nullptr);
  }
}